// Round 3
// baseline (337.384 us; speedup 1.0000x reference)
//
#include <hip/hip_runtime.h>
#include <math.h>

// Problem constants (from reference)
#define LL   2048     // seq len
#define BB   64       // batch
#define EE   256      // embedding
#define HH   128      // lstm hidden per dir
#define GG   512      // 4*H gates
#define TT   128      // utterances (L / SEP_EVERY)
#define SEPT 50256

typedef __attribute__((ext_vector_type(2))) float f32x2;

// ---------------------------------------------------------------------------
// Kernel 1: per-column prefix-scan of SEP flags -> seg[t,b], plus per-(utt,b)
// token counts and start offsets (segments are contiguous per column).
// ---------------------------------------------------------------------------
__global__ __launch_bounds__(256) void segscan_k(
    const int* __restrict__ x, int* __restrict__ seg,
    int* __restrict__ cnt, int* __restrict__ start)
{
    int b   = blockIdx.x;    // 0..63
    int tid = threadIdx.x;   // 0..255, 8 tokens each
    __shared__ int tsum[256];
    __shared__ int ucnt[TT];
    __shared__ int ustart[TT];

    int flags[8];
    int local = 0;
#pragma unroll
    for (int i = 0; i < 8; i++) {
        int t = tid * 8 + i;
        flags[i] = (x[t * BB + b] == SEPT) ? 1 : 0;
        local += flags[i];
    }
    tsum[tid] = local;
    __syncthreads();
    int val = local;
    for (int off = 1; off < 256; off <<= 1) {
        int other = (tid >= off) ? tsum[tid - off] : 0;
        __syncthreads();
        val += other;
        tsum[tid] = val;
        __syncthreads();
    }
    int excl = val - local;   // seps strictly before this thread's chunk

    if (tid < TT) ucnt[tid] = 0;
    __syncthreads();
    int run = excl;
#pragma unroll
    for (int i = 0; i < 8; i++) {
        int t = tid * 8 + i;
        int s = run;                 // seg id = #seps before this token
        seg[t * BB + b] = s;
        run += flags[i];
        if (s < TT) atomicAdd(&ucnt[s], 1);
    }
    __syncthreads();
    if (tid == 0) {
        int acc = 0;
        for (int u = 0; u < TT; u++) { ustart[u] = acc; acc += ucnt[u]; }
    }
    __syncthreads();
    if (tid < TT) {
        cnt[tid * BB + b]   = ucnt[tid];
        start[tid * BB + b] = ustart[tid];
    }
}

// ---------------------------------------------------------------------------
// Kernel 2: embedding gather + mean pool. One block per (utt,b).
// ---------------------------------------------------------------------------
__global__ __launch_bounds__(256) void pool_k(
    const int* __restrict__ x, const float* __restrict__ emb,
    const int* __restrict__ cnt, const int* __restrict__ start,
    float* __restrict__ up)
{
    int bid = blockIdx.x;        // u*64+b
    int b   = bid & 63;
    int e   = threadIdx.x;       // 0..255
    int c   = cnt[bid];
    int st  = start[bid];
    float acc = 0.f;
    for (int j = 0; j < c; j++) {
        int tok = x[(st + j) * BB + b];     // wave-uniform -> scalar load
        acc += emb[tok * EE + e];           // coalesced 1KB row
    }
    up[bid * EE + e] = (c > 0) ? acc / (float)c : 0.f;
}

// ---------------------------------------------------------------------------
// Kernel 3: xp = u @ W_cat^T + (b_ih + b_hh).  fp32 register-tiled GEMM.
// ---------------------------------------------------------------------------
__global__ __launch_bounds__(256) void xp_gemm_k(
    const float* __restrict__ A,
    const float* __restrict__ wf, const float* __restrict__ wb,
    const float* __restrict__ bihf, const float* __restrict__ bhhf,
    const float* __restrict__ bihb, const float* __restrict__ bhhb,
    float* __restrict__ C)
{
    __shared__ float As[32][64];    // [k][m]
    __shared__ float Bs[32][64];    // [k][n]
    int tid  = threadIdx.x;
    int row0 = blockIdx.x * 64;     // 128 blocks
    int col0 = blockIdx.y * 64;     // 16 blocks
    int tx = tid & 15, ty = tid >> 4;
    float acc[4][4] = {};

    for (int k0 = 0; k0 < EE; k0 += 32) {
#pragma unroll
        for (int i = 0; i < 2; i++) {
            int idx = tid + i * 256;       // float4 slot
            int m   = idx >> 3;
            int k4  = idx & 7;
            float4 av = *(const float4*)(A + (size_t)(row0 + m) * EE + k0 + k4 * 4);
            As[k4 * 4 + 0][m] = av.x; As[k4 * 4 + 1][m] = av.y;
            As[k4 * 4 + 2][m] = av.z; As[k4 * 4 + 3][m] = av.w;
        }
#pragma unroll
        for (int i = 0; i < 2; i++) {
            int idx = tid + i * 256;
            int n   = idx >> 3;
            int k4  = idx & 7;
            int gc  = col0 + n;
            const float* wsrc = (gc < GG) ? (wf + (size_t)gc * EE)
                                          : (wb + (size_t)(gc - GG) * EE);
            float4 bv = *(const float4*)(wsrc + k0 + k4 * 4);
            Bs[k4 * 4 + 0][n] = bv.x; Bs[k4 * 4 + 1][n] = bv.y;
            Bs[k4 * 4 + 2][n] = bv.z; Bs[k4 * 4 + 3][n] = bv.w;
        }
        __syncthreads();
#pragma unroll
        for (int k = 0; k < 32; k++) {
            float a4[4], b4[4];
            *(float4*)a4 = *(const float4*)&As[k][ty * 4];
            *(float4*)b4 = *(const float4*)&Bs[k][tx * 4];
#pragma unroll
            for (int i = 0; i < 4; i++)
#pragma unroll
                for (int j = 0; j < 4; j++)
                    acc[i][j] += a4[i] * b4[j];
        }
        __syncthreads();
    }
#pragma unroll
    for (int i = 0; i < 4; i++) {
        int r = row0 + ty * 4 + i;
#pragma unroll
        for (int j = 0; j < 4; j++) {
            int gc = col0 + tx * 4 + j;
            float bias = (gc < GG) ? (bihf[gc] + bhhf[gc])
                                   : (bihb[gc - GG] + bhhb[gc - GG]);
            C[(size_t)r * 1024 + gc] = acc[i][j] + bias;
        }
    }
}

// ---------------------------------------------------------------------------
// Fast activations
// ---------------------------------------------------------------------------
__device__ __forceinline__ float sigm_f(float x) {
    return 1.f / (1.f + __expf(-x));
}
__device__ __forceinline__ float tanh_f(float x) {
    return 1.f - 2.f / (__expf(2.f * x) + 1.f);
}

// ---------------------------------------------------------------------------
// Kernel 4: LSTM recurrence, v3.
// One block per (dir, batch) = 128 blocks, 512 threads (8 waves).
// Wave w owns BOTH k-slice [16w,16w+16) AND unit range [16w,16w+16):
//   phase 1: wave reads its own h slice (wave-private, no barrier), computes
//            partials for all 512 gates with v_pk_fma_f32 against weights
//            PINNED in VGPRs (inline-asm pin prevents the compiler from
//            sinking the loop-invariant loads into the loop — round-2 bug:
//            VGPR_Count=84 proved weights were reloaded every step).
//   ONE __syncthreads (part[] double-buffered by step parity).
//   phase 2: lane l reduces gate 128*(l>>4)+16w+(l&15): 8 part reads + 1 exp,
//            3x shfl_xor gathers i,f,g,o to t=0 lanes, which update c/h and
//            write h back to their OWN wave's LDS slice (consumed by the same
//            wave next step -> no second barrier).
// ---------------------------------------------------------------------------
__global__ __launch_bounds__(512, 2) void lstm_rec_k(
    const float* __restrict__ xp,            // [T*B][1024]
    const float* __restrict__ whh_f, const float* __restrict__ whh_b,
    float* __restrict__ hout)                // [2][T][B][H]
{
    int bid = blockIdx.x;
    int dir = bid >> 6;
    int b   = bid & 63;
    int tid = threadIdx.x;
    int wv  = tid >> 6;      // wave id 0..7 -> k-slice AND unit-slice
    int l   = tid & 63;
    const float* whh = dir ? whh_b : whh_f;

    // --- weights, packed pairs, pinned in VGPRs -------------------------
    // w2[j][k2] = ( whh[(l+64j)*128 + 16wv + 2k2], ...+1 )
    f32x2 w2[8][8];
#pragma unroll
    for (int j = 0; j < 8; j++) {
        const float* src = whh + (size_t)(l + 64 * j) * HH + 16 * wv;
#pragma unroll
        for (int k4 = 0; k4 < 4; k4++) {
            float4 v4 = *(const float4*)(src + k4 * 4);
            w2[j][k4 * 2 + 0] = f32x2{v4.x, v4.y};
            w2[j][k4 * 2 + 1] = f32x2{v4.z, v4.w};
        }
    }
#pragma unroll
    for (int j = 0; j < 8; j++)
#pragma unroll
        for (int k2 = 0; k2 < 8; k2++)
            asm volatile("" : "+v"(w2[j][k2]));   // pin: no remat/sink

    __shared__ __align__(16) float h_lds[HH];          // wave w uses [16w,16w+16)
    __shared__ float part[2][8][512];                  // [parity][k-wave][gate]

    int t_type = l >> 4;          // 0:i 1:f 2:g 3:o
    int u16    = l & 15;
    int g2     = t_type * 128 + 16 * wv + u16;         // gate reduced in phase 2
    int unit   = 16 * wv + u16;

    float c = 0.f;                                     // valid in t_type==0 lanes
    if (l < 16) h_lds[unit] = 0.f;
    __syncthreads();

    int t0   = dir ? (TT - 1) : 0;
    float xg = xp[(size_t)(t0 * BB + b) * 1024 + dir * GG + g2];

    for (int s = 0; s < TT; s++) {
        int p = s & 1;
        // ---- phase 1: partial dots over own k-slice ----
        float4 hr0 = *(const float4*)&h_lds[16 * wv + 0];
        float4 hr1 = *(const float4*)&h_lds[16 * wv + 4];
        float4 hr2 = *(const float4*)&h_lds[16 * wv + 8];
        float4 hr3 = *(const float4*)&h_lds[16 * wv + 12];
        f32x2 h2[8];
        h2[0] = f32x2{hr0.x, hr0.y}; h2[1] = f32x2{hr0.z, hr0.w};
        h2[2] = f32x2{hr1.x, hr1.y}; h2[3] = f32x2{hr1.z, hr1.w};
        h2[4] = f32x2{hr2.x, hr2.y}; h2[5] = f32x2{hr2.z, hr2.w};
        h2[6] = f32x2{hr3.x, hr3.y}; h2[7] = f32x2{hr3.z, hr3.w};

#pragma unroll
        for (int j = 0; j < 8; j++) {
            f32x2 acc = {0.f, 0.f};
#pragma unroll
            for (int k2 = 0; k2 < 8; k2++)
                asm("v_pk_fma_f32 %0, %1, %2, %0"
                    : "+v"(acc) : "v"(w2[j][k2]), "v"(h2[k2]));
            part[p][wv][l + 64 * j] = acc.x + acc.y;
        }

        // prefetch next step's xp while FMAs drain
        float xg_next = xg;
        if (s < TT - 1) {
            int tn = dir ? (TT - 2 - s) : (s + 1);
            xg_next = xp[(size_t)(tn * BB + b) * 1024 + dir * GG + g2];
        }
        __syncthreads();

        // ---- phase 2: reduce gate g2, activate, combine, update ----
        float sum = xg;
#pragma unroll
        for (int w2i = 0; w2i < 8; w2i++)
            sum += part[p][w2i][g2];

        bool is_g = (t_type == 2);
        float e  = __expf(is_g ? (2.f * sum) : (-sum));
        float av = is_g ? (1.f - 2.f / (e + 1.f)) : (1.f / (1.f + e));

        float r1 = __shfl_xor(av, 16);   // t0 lanes: f-act
        float r2 = __shfl_xor(av, 32);   // t0 lanes: tanh(g)
        float r3 = __shfl_xor(r1, 32);   // t0 lanes: o-act

        if (l < 16) {
            c = r1 * c + av * r2;        // c = sig(f)*c + sig(i)*tanh(g)
            float h = r3 * tanh_f(c);
            h_lds[unit] = h;             // own wave's slice -> no barrier
            int t = dir ? (TT - 1 - s) : s;
            hout[((size_t)(dir * TT + t) * BB + b) * HH + unit] = h;
        }
        xg = xg_next;
    }
}

// ---------------------------------------------------------------------------
// Kernel 5: head — logits, softmax, argmax, chosen policy. One wave per row.
// ---------------------------------------------------------------------------
__global__ __launch_bounds__(256) void head_k(
    const float* __restrict__ hbuf,           // [2][T][B][H]
    const float* __restrict__ wout, const float* __restrict__ bout,
    float* __restrict__ out)
{
    int wid  = threadIdx.x >> 6;
    int lane = threadIdx.x & 63;
    int row  = blockIdx.x * 4 + wid;          // t*64+b, 0..8191
    int t = row >> 6, b = row & 63;
    const float* hf = hbuf + ((size_t)(t)      * BB + b) * HH;
    const float* hb = hbuf + ((size_t)(TT + t) * BB + b) * HH;

    float l0 = 0.f, l1 = 0.f, v;
    v = hf[lane];      l0 += v * wout[lane];           l1 += v * wout[256 + lane];
    v = hf[lane + 64]; l0 += v * wout[64 + lane];      l1 += v * wout[320 + lane];
    v = hb[lane];      l0 += v * wout[128 + lane];     l1 += v * wout[384 + lane];
    v = hb[lane + 64]; l0 += v * wout[192 + lane];     l1 += v * wout[448 + lane];
#pragma unroll
    for (int off = 32; off > 0; off >>= 1) {
        l0 += __shfl_down(l0, off);
        l1 += __shfl_down(l1, off);
    }
    if (lane == 0) {
        l0 += bout[0]; l1 += bout[1];
        float m  = fmaxf(l0, l1);
        float e0 = __expf(l0 - m), e1 = __expf(l1 - m);
        float inv = 1.f / (e0 + e1);
        float p0 = e0 * inv, p1 = e1 * inv;
        int amax = (l1 > l0) ? 1 : 0;          // tie -> 0, matches jnp.argmax
        out[(size_t)row * 2 + 0] = l0;
        out[(size_t)row * 2 + 1] = l1;
        out[16384 + (size_t)row * 2 + 0] = p0;
        out[16384 + (size_t)row * 2 + 1] = p1;
        out[32768 + row] = amax ? p1 : p0;
        out[40960 + row] = (float)amax;
    }
}

// ---------------------------------------------------------------------------
// Kernel 6: expand utterance mask to tokens, write masked input as float.
// ---------------------------------------------------------------------------
__global__ __launch_bounds__(256) void mask_k(
    const int* __restrict__ x, const int* __restrict__ seg,
    const float* __restrict__ umask, float* __restrict__ out4)
{
    int idx = blockIdx.x * 256 + threadIdx.x;    // < 131072
    int b = idx & 63;
    int s = seg[idx];
    if (s > TT - 1) s = TT - 1;                  // jnp OOB indexing clamps
    if (s < 0) s = 0;
    float keep = umask[s * BB + b];
    out4[idx] = (keep != 0.f) ? (float)x[idx] : 0.f;
}

// ---------------------------------------------------------------------------
extern "C" void kernel_launch(void* const* d_in, const int* in_sizes, int n_in,
                              void* d_out, int out_size, void* d_ws, size_t ws_size,
                              hipStream_t stream)
{
    const int*   x    = (const int*)  d_in[0];
    const float* emb  = (const float*)d_in[1];
    const float* wihf = (const float*)d_in[2];
    const float* whhf = (const float*)d_in[3];
    const float* bihf = (const float*)d_in[4];
    const float* bhhf = (const float*)d_in[5];
    const float* wihb = (const float*)d_in[6];
    const float* whhb = (const float*)d_in[7];
    const float* bihb = (const float*)d_in[8];
    const float* bhhb = (const float*)d_in[9];
    const float* wout = (const float*)d_in[10];
    const float* bout = (const float*)d_in[11];
    float* out = (float*)d_out;
    char*  ws  = (char*)d_ws;

    // workspace layout (bytes)
    int*   seg   = (int*)  (ws + 0);         // 2048*64*4   = 524288
    int*   cnt   = (int*)  (ws + 524288);    // 128*64*4    = 32768
    int*   start = (int*)  (ws + 557056);    // 32768
    float* up    = (float*)(ws + 589824);    // 128*64*256*4  = 8 MB
    float* xp    = (float*)(ws + 8978432);   // 128*64*1024*4 = 32 MB
    float* hbuf  = (float*)(ws + 42532864);  // 2*128*64*128*4 = 8 MB

    segscan_k<<<64, 256, 0, stream>>>(x, seg, cnt, start);
    pool_k<<<TT * BB, 256, 0, stream>>>(x, emb, cnt, start, up);
    xp_gemm_k<<<dim3(128, 16), 256, 0, stream>>>(up, wihf, wihb, bihf, bhhf, bihb, bhhb, xp);
    lstm_rec_k<<<128, 512, 0, stream>>>(xp, whhf, whhb, hbuf);
    head_k<<<2048, 256, 0, stream>>>(hbuf, wout, bout, out);
    mask_k<<<512, 256, 0, stream>>>(x, seg, out + 40960, out + 49152);
}

// Round 6
// 325.791 us; speedup vs baseline: 1.0356x; 1.0356x over previous
//
#include <hip/hip_runtime.h>
#include <math.h>

// Problem constants (from reference)
#define LL   2048     // seq len
#define BB   64       // batch
#define EE   256      // embedding
#define HH   128      // lstm hidden per dir
#define GG   512      // 4*H gates
#define TT   128      // utterances (L / SEP_EVERY)
#define SEPT 50256

// ---------------------------------------------------------------------------
// Kernel 1: per-column prefix-scan of SEP flags -> seg[t,b], plus per-(utt,b)
// token counts and start offsets (segments are contiguous per column).
// ---------------------------------------------------------------------------
__global__ __launch_bounds__(256) void segscan_k(
    const int* __restrict__ x, int* __restrict__ seg,
    int* __restrict__ cnt, int* __restrict__ start)
{
    int b   = blockIdx.x;    // 0..63
    int tid = threadIdx.x;   // 0..255, 8 tokens each
    __shared__ int tsum[256];
    __shared__ int ucnt[TT];
    __shared__ int ustart[TT];

    int flags[8];
    int local = 0;
#pragma unroll
    for (int i = 0; i < 8; i++) {
        int t = tid * 8 + i;
        flags[i] = (x[t * BB + b] == SEPT) ? 1 : 0;
        local += flags[i];
    }
    tsum[tid] = local;
    __syncthreads();
    int val = local;
    for (int off = 1; off < 256; off <<= 1) {
        int other = (tid >= off) ? tsum[tid - off] : 0;
        __syncthreads();
        val += other;
        tsum[tid] = val;
        __syncthreads();
    }
    int excl = val - local;   // seps strictly before this thread's chunk

    if (tid < TT) ucnt[tid] = 0;
    __syncthreads();
    int run = excl;
#pragma unroll
    for (int i = 0; i < 8; i++) {
        int t = tid * 8 + i;
        int s = run;                 // seg id = #seps before this token
        seg[t * BB + b] = s;
        run += flags[i];
        if (s < TT) atomicAdd(&ucnt[s], 1);
    }
    __syncthreads();
    if (tid == 0) {
        int acc = 0;
        for (int u = 0; u < TT; u++) { ustart[u] = acc; acc += ucnt[u]; }
    }
    __syncthreads();
    if (tid < TT) {
        cnt[tid * BB + b]   = ucnt[tid];
        start[tid * BB + b] = ustart[tid];
    }
}

// ---------------------------------------------------------------------------
// Kernel 2: embedding gather + mean pool. One WAVE per (utt,b); lane holds a
// float4 column slice -> one coalesced 1KB row read per token.
// GRID MUST BE 2048 blocks (8192 bids / 4 waves per block) — r4 bug was 512.
// ---------------------------------------------------------------------------
__global__ __launch_bounds__(256) void pool_k(
    const int* __restrict__ x, const float* __restrict__ emb,
    const int* __restrict__ cnt, const int* __restrict__ start,
    float* __restrict__ up)
{
    int wid  = threadIdx.x >> 6;
    int lane = threadIdx.x & 63;
    int bid  = blockIdx.x * 4 + wid;   // u*64+b, grid 2048 -> bid in [0,8192)
    int b    = bid & 63;
    int c    = cnt[bid];
    int st   = start[bid];

    float4 acc = {0.f, 0.f, 0.f, 0.f};
    int tok = (c > 0) ? x[st * BB + b] : 0;
    for (int j = 0; j < c; j++) {
        int tok_n = (j + 1 < c) ? x[(st + j + 1) * BB + b] : 0;  // prefetch
        float4 v = ((const float4*)(emb + (size_t)tok * EE))[lane];
        acc.x += v.x; acc.y += v.y; acc.z += v.z; acc.w += v.w;
        tok = tok_n;
    }
    float inv = (c > 0) ? 1.f / (float)c : 0.f;
    float4 r = {acc.x * inv, acc.y * inv, acc.z * inv, acc.w * inv};
    ((float4*)(up + (size_t)bid * EE))[lane] = r;
}

// ---------------------------------------------------------------------------
// Kernel 3: xp = u @ W_cat^T + (b_ih + b_hh).  fp32 register-tiled GEMM.
// ---------------------------------------------------------------------------
__global__ __launch_bounds__(256) void xp_gemm_k(
    const float* __restrict__ A,
    const float* __restrict__ wf, const float* __restrict__ wb,
    const float* __restrict__ bihf, const float* __restrict__ bhhf,
    const float* __restrict__ bihb, const float* __restrict__ bhhb,
    float* __restrict__ C)
{
    __shared__ float As[32][64];    // [k][m]
    __shared__ float Bs[32][64];    // [k][n]
    int tid  = threadIdx.x;
    int row0 = blockIdx.x * 64;     // 128 blocks
    int col0 = blockIdx.y * 64;     // 16 blocks
    int tx = tid & 15, ty = tid >> 4;
    float acc[4][4] = {};

    for (int k0 = 0; k0 < EE; k0 += 32) {
#pragma unroll
        for (int i = 0; i < 2; i++) {
            int idx = tid + i * 256;       // float4 slot
            int m   = idx >> 3;
            int k4  = idx & 7;
            float4 av = *(const float4*)(A + (size_t)(row0 + m) * EE + k0 + k4 * 4);
            As[k4 * 4 + 0][m] = av.x; As[k4 * 4 + 1][m] = av.y;
            As[k4 * 4 + 2][m] = av.z; As[k4 * 4 + 3][m] = av.w;
        }
#pragma unroll
        for (int i = 0; i < 2; i++) {
            int idx = tid + i * 256;
            int n   = idx >> 3;
            int k4  = idx & 7;
            int gc  = col0 + n;
            const float* wsrc = (gc < GG) ? (wf + (size_t)gc * EE)
                                          : (wb + (size_t)(gc - GG) * EE);
            float4 bv = *(const float4*)(wsrc + k0 + k4 * 4);
            Bs[k4 * 4 + 0][n] = bv.x; Bs[k4 * 4 + 1][n] = bv.y;
            Bs[k4 * 4 + 2][n] = bv.z; Bs[k4 * 4 + 3][n] = bv.w;
        }
        __syncthreads();
#pragma unroll
        for (int k = 0; k < 32; k++) {
            float a4[4], b4[4];
            *(float4*)a4 = *(const float4*)&As[k][ty * 4];
            *(float4*)b4 = *(const float4*)&Bs[k][tx * 4];
#pragma unroll
            for (int i = 0; i < 4; i++)
#pragma unroll
                for (int j = 0; j < 4; j++)
                    acc[i][j] += a4[i] * b4[j];
        }
        __syncthreads();
    }
#pragma unroll
    for (int i = 0; i < 4; i++) {
        int r = row0 + ty * 4 + i;
#pragma unroll
        for (int j = 0; j < 4; j++) {
            int gc = col0 + tx * 4 + j;
            float bias = (gc < GG) ? (bihf[gc] + bhhf[gc])
                                   : (bihb[gc - GG] + bhhb[gc - GG]);
            C[(size_t)r * 1024 + gc] = acc[i][j] + bias;
        }
    }
}

// ---------------------------------------------------------------------------
// Fast activations
// ---------------------------------------------------------------------------
__device__ __forceinline__ float sigm_f(float x) {
    return 1.f / (1.f + __expf(-x));
}
__device__ __forceinline__ float tanh_f(float x) {
    return 1.f - 2.f / (__expf(2.f * x) + 1.f);
}

// ---------------------------------------------------------------------------
// Kernel 4: LSTM recurrence, v4.
// One block per (dir, batch) = 128 blocks, 512 threads (8 waves).
// amdgpu_waves_per_eu(2,2): cap max occupancy at 2 waves/EU so the register
// allocator gets a 256-VGPR budget and keeps the 128 weight floats resident.
// (r2/r3: default heuristic targeted the 6-waves tier -> 84 VGPRs ->
// weights reloaded from memory every step.)
// Wave w owns k-slice AND unit-slice [16w,16w+16): phase-1 h reads and
// phase-2 h writes touch only the wave's own slice -> ONE barrier per step.
// part[] bank-swizzled: phys(g) = t*128 + (((g&127) + 8t) & 127) -> exact
// 2-way LDS access everywhere (2-way free; r3 unswizzled was 4-way, 2.1M
// conflict cycles).
// ---------------------------------------------------------------------------
__global__ __launch_bounds__(512)
__attribute__((amdgpu_waves_per_eu(2, 2)))
void lstm_rec_k(
    const float* __restrict__ xp,            // [T*B][1024]
    const float* __restrict__ whh_f, const float* __restrict__ whh_b,
    float* __restrict__ hout)                // [2][T][B][H]
{
    int bid = blockIdx.x;
    int dir = bid >> 6;
    int b   = bid & 63;
    int tid = threadIdx.x;
    int wv  = tid >> 6;      // wave id 0..7 -> k-slice and unit-slice
    int l   = tid & 63;
    const float* whh = dir ? whh_b : whh_f;

    // weights: w4[j][k4] = whh[(l+64j)*128 + 16wv + 4k4 .. +3], 128 floats
    float4 w4[8][4];
#pragma unroll
    for (int j = 0; j < 8; j++) {
        const float* src = whh + (size_t)(l + 64 * j) * HH + 16 * wv;
#pragma unroll
        for (int k4 = 0; k4 < 4; k4++)
            w4[j][k4] = *(const float4*)(src + k4 * 4);
    }

    __shared__ __align__(16) float h_lds[HH];      // wave w: [16w,16w+16)
    __shared__ float part[2][8][GG];               // [parity][k-wave][swz gate]

    int t_type = l >> 4;          // 0:i 1:f 2:g 3:o
    int u16    = l & 15;
    int unit   = 16 * wv + u16;
    int g2     = t_type * 128 + unit;              // gate reduced in phase 2
    int phys2  = t_type * 128 + ((unit + 8 * t_type) & 127);

    // phase-1 write indices (swizzled), g = l + 64j
    int physw[8];
#pragma unroll
    for (int j = 0; j < 8; j++) {
        int t = j >> 1;
        physw[j] = t * 128 + ((64 * (j & 1) + l + 8 * t) & 127);
    }

    float c = 0.f;                                 // valid in t_type==0 lanes
    if (l < 16) h_lds[unit] = 0.f;
    __syncthreads();

    int t0   = dir ? (TT - 1) : 0;
    float xg = xp[(size_t)(t0 * BB + b) * 1024 + dir * GG + g2];

    for (int s = 0; s < TT; s++) {
        int p = s & 1;
        // ---- phase 1: partial dots over own k-slice (wave-private h) ----
        float4 h0 = *(const float4*)&h_lds[16 * wv + 0];
        float4 h1 = *(const float4*)&h_lds[16 * wv + 4];
        float4 h2 = *(const float4*)&h_lds[16 * wv + 8];
        float4 h3 = *(const float4*)&h_lds[16 * wv + 12];

#pragma unroll
        for (int j = 0; j < 8; j++) {
            float a0 = w4[j][0].x * h0.x + w4[j][0].y * h0.y
                     + w4[j][0].z * h0.z + w4[j][0].w * h0.w;
            float a1 = w4[j][1].x * h1.x + w4[j][1].y * h1.y
                     + w4[j][1].z * h1.z + w4[j][1].w * h1.w;
            float a2 = w4[j][2].x * h2.x + w4[j][2].y * h2.y
                     + w4[j][2].z * h2.z + w4[j][2].w * h2.w;
            float a3 = w4[j][3].x * h3.x + w4[j][3].y * h3.y
                     + w4[j][3].z * h3.z + w4[j][3].w * h3.w;
            part[p][wv][physw[j]] = (a0 + a1) + (a2 + a3);
        }

        // prefetch next step's xp while FMAs drain
        float xg_next = xg;
        if (s < TT - 1) {
            int tn = dir ? (TT - 2 - s) : (s + 1);
            xg_next = xp[(size_t)(tn * BB + b) * 1024 + dir * GG + g2];
        }
        __syncthreads();

        // ---- phase 2: reduce gate g2, activate, combine, update ----
        float sum = xg;
#pragma unroll
        for (int w2i = 0; w2i < 8; w2i++)
            sum += part[p][w2i][phys2];

        bool is_g = (t_type == 2);
        float e  = __expf(is_g ? (2.f * sum) : (-sum));
        float av = is_g ? (1.f - 2.f / (e + 1.f)) : (1.f / (1.f + e));

        float r1 = __shfl_xor(av, 16);   // t0 lanes: sig(f)
        float r2 = __shfl_xor(av, 32);   // t0 lanes: tanh(g)
        float r3 = __shfl_xor(r1, 32);   // t0 lanes: sig(o)

        if (l < 16) {
            c = r1 * c + av * r2;        // c = sig(f)*c + sig(i)*tanh(g)
            float h = r3 * tanh_f(c);
            h_lds[unit] = h;             // own wave's slice -> no 2nd barrier
            int t = dir ? (TT - 1 - s) : s;
            hout[((size_t)(dir * TT + t) * BB + b) * HH + unit] = h;
        }
        xg = xg_next;
    }
}

// ---------------------------------------------------------------------------
// Kernel 5: head — logits, softmax, argmax, chosen policy. One wave per row.
// ---------------------------------------------------------------------------
__global__ __launch_bounds__(256) void head_k(
    const float* __restrict__ hbuf,           // [2][T][B][H]
    const float* __restrict__ wout, const float* __restrict__ bout,
    float* __restrict__ out)
{
    int wid  = threadIdx.x >> 6;
    int lane = threadIdx.x & 63;
    int row  = blockIdx.x * 4 + wid;          // t*64+b, 0..8191
    int t = row >> 6, b = row & 63;
    const float* hf = hbuf + ((size_t)(t)      * BB + b) * HH;
    const float* hb = hbuf + ((size_t)(TT + t) * BB + b) * HH;

    float l0 = 0.f, l1 = 0.f, v;
    v = hf[lane];      l0 += v * wout[lane];           l1 += v * wout[256 + lane];
    v = hf[lane + 64]; l0 += v * wout[64 + lane];      l1 += v * wout[320 + lane];
    v = hb[lane];      l0 += v * wout[128 + lane];     l1 += v * wout[384 + lane];
    v = hb[lane + 64]; l0 += v * wout[192 + lane];     l1 += v * wout[448 + lane];
#pragma unroll
    for (int off = 32; off > 0; off >>= 1) {
        l0 += __shfl_down(l0, off);
        l1 += __shfl_down(l1, off);
    }
    if (lane == 0) {
        l0 += bout[0]; l1 += bout[1];
        float m  = fmaxf(l0, l1);
        float e0 = __expf(l0 - m), e1 = __expf(l1 - m);
        float inv = 1.f / (e0 + e1);
        float p0 = e0 * inv, p1 = e1 * inv;
        int amax = (l1 > l0) ? 1 : 0;          // tie -> 0, matches jnp.argmax
        out[(size_t)row * 2 + 0] = l0;
        out[(size_t)row * 2 + 1] = l1;
        out[16384 + (size_t)row * 2 + 0] = p0;
        out[16384 + (size_t)row * 2 + 1] = p1;
        out[32768 + row] = amax ? p1 : p0;
        out[40960 + row] = (float)amax;
    }
}

// ---------------------------------------------------------------------------
// Kernel 6: expand utterance mask to tokens, write masked input as float.
// ---------------------------------------------------------------------------
__global__ __launch_bounds__(256) void mask_k(
    const int* __restrict__ x, const int* __restrict__ seg,
    const float* __restrict__ umask, float* __restrict__ out4)
{
    int idx = blockIdx.x * 256 + threadIdx.x;    // < 131072
    int b = idx & 63;
    int s = seg[idx];
    if (s > TT - 1) s = TT - 1;                  // jnp OOB indexing clamps
    if (s < 0) s = 0;
    float keep = umask[s * BB + b];
    out4[idx] = (keep != 0.f) ? (float)x[idx] : 0.f;
}

// ---------------------------------------------------------------------------
extern "C" void kernel_launch(void* const* d_in, const int* in_sizes, int n_in,
                              void* d_out, int out_size, void* d_ws, size_t ws_size,
                              hipStream_t stream)
{
    const int*   x    = (const int*)  d_in[0];
    const float* emb  = (const float*)d_in[1];
    const float* wihf = (const float*)d_in[2];
    const float* whhf = (const float*)d_in[3];
    const float* bihf = (const float*)d_in[4];
    const float* bhhf = (const float*)d_in[5];
    const float* wihb = (const float*)d_in[6];
    const float* whhb = (const float*)d_in[7];
    const float* bihb = (const float*)d_in[8];
    const float* bhhb = (const float*)d_in[9];
    const float* wout = (const float*)d_in[10];
    const float* bout = (const float*)d_in[11];
    float* out = (float*)d_out;
    char*  ws  = (char*)d_ws;

    // workspace layout (bytes)
    int*   seg   = (int*)  (ws + 0);         // 2048*64*4   = 524288
    int*   cnt   = (int*)  (ws + 524288);    // 128*64*4    = 32768
    int*   start = (int*)  (ws + 557056);    // 32768
    float* up    = (float*)(ws + 589824);    // 128*64*256*4  = 8 MB
    float* xp    = (float*)(ws + 8978432);   // 128*64*1024*4 = 32 MB
    float* hbuf  = (float*)(ws + 42532864);  // 2*128*64*128*4 = 8 MB

    segscan_k<<<64, 256, 0, stream>>>(x, seg, cnt, start);
    pool_k<<<2048, 256, 0, stream>>>(x, emb, cnt, start, up);   // 8192 waves
    xp_gemm_k<<<dim3(128, 16), 256, 0, stream>>>(up, wihf, wihb, bihf, bhhf, bihb, bhhb, xp);
    lstm_rec_k<<<128, 512, 0, stream>>>(xp, whhf, whhb, hbuf);
    head_k<<<2048, 256, 0, stream>>>(hbuf, wout, bout, out);
    mask_k<<<512, 256, 0, stream>>>(x, seg, out + 40960, out + 49152);
}

// Round 7
// 325.722 us; speedup vs baseline: 1.0358x; 1.0002x over previous
//
#include <hip/hip_runtime.h>
#include <math.h>

// Problem constants (from reference)
#define LL   2048     // seq len
#define BB   64       // batch
#define EE   256      // embedding
#define HH   128      // lstm hidden per dir
#define GG   512      // 4*H gates
#define TT   128      // utterances (L / SEP_EVERY)
#define SEPT 50256

// ---------------------------------------------------------------------------
// Kernel 1: per-column prefix-scan of SEP flags -> seg[t,b], plus per-(utt,b)
// token counts and start offsets (segments are contiguous per column).
// ---------------------------------------------------------------------------
__global__ __launch_bounds__(256) void segscan_k(
    const int* __restrict__ x, int* __restrict__ seg,
    int* __restrict__ cnt, int* __restrict__ start)
{
    int b   = blockIdx.x;    // 0..63
    int tid = threadIdx.x;   // 0..255, 8 tokens each
    __shared__ int tsum[256];
    __shared__ int ucnt[TT];
    __shared__ int ustart[TT];

    int flags[8];
    int local = 0;
#pragma unroll
    for (int i = 0; i < 8; i++) {
        int t = tid * 8 + i;
        flags[i] = (x[t * BB + b] == SEPT) ? 1 : 0;
        local += flags[i];
    }
    tsum[tid] = local;
    __syncthreads();
    int val = local;
    for (int off = 1; off < 256; off <<= 1) {
        int other = (tid >= off) ? tsum[tid - off] : 0;
        __syncthreads();
        val += other;
        tsum[tid] = val;
        __syncthreads();
    }
    int excl = val - local;   // seps strictly before this thread's chunk

    if (tid < TT) ucnt[tid] = 0;
    __syncthreads();
    int run = excl;
#pragma unroll
    for (int i = 0; i < 8; i++) {
        int t = tid * 8 + i;
        int s = run;                 // seg id = #seps before this token
        seg[t * BB + b] = s;
        run += flags[i];
        if (s < TT) atomicAdd(&ucnt[s], 1);
    }
    __syncthreads();
    if (tid == 0) {
        int acc = 0;
        for (int u = 0; u < TT; u++) { ustart[u] = acc; acc += ucnt[u]; }
    }
    __syncthreads();
    if (tid < TT) {
        cnt[tid * BB + b]   = ucnt[tid];
        start[tid * BB + b] = ustart[tid];
    }
}

// ---------------------------------------------------------------------------
// Kernel 2: embedding gather + mean pool. One WAVE per (utt,b); lane holds a
// float4 column slice -> one coalesced 1KB row read per token. Grid = 2048.
// ---------------------------------------------------------------------------
__global__ __launch_bounds__(256) void pool_k(
    const int* __restrict__ x, const float* __restrict__ emb,
    const int* __restrict__ cnt, const int* __restrict__ start,
    float* __restrict__ up)
{
    int wid  = threadIdx.x >> 6;
    int lane = threadIdx.x & 63;
    int bid  = blockIdx.x * 4 + wid;   // u*64+b, bid in [0,8192)
    int b    = bid & 63;
    int c    = cnt[bid];
    int st   = start[bid];

    float4 acc = {0.f, 0.f, 0.f, 0.f};
    int tok = (c > 0) ? x[st * BB + b] : 0;
    for (int j = 0; j < c; j++) {
        int tok_n = (j + 1 < c) ? x[(st + j + 1) * BB + b] : 0;  // prefetch
        float4 v = ((const float4*)(emb + (size_t)tok * EE))[lane];
        acc.x += v.x; acc.y += v.y; acc.z += v.z; acc.w += v.w;
        tok = tok_n;
    }
    float inv = (c > 0) ? 1.f / (float)c : 0.f;
    float4 r = {acc.x * inv, acc.y * inv, acc.z * inv, acc.w * inv};
    ((float4*)(up + (size_t)bid * EE))[lane] = r;
}

// ---------------------------------------------------------------------------
// Kernel 3: xp = u @ W_cat^T + (b_ih + b_hh).  fp32 register-tiled GEMM.
// ---------------------------------------------------------------------------
__global__ __launch_bounds__(256) void xp_gemm_k(
    const float* __restrict__ A,
    const float* __restrict__ wf, const float* __restrict__ wb,
    const float* __restrict__ bihf, const float* __restrict__ bhhf,
    const float* __restrict__ bihb, const float* __restrict__ bhhb,
    float* __restrict__ C)
{
    __shared__ float As[32][64];    // [k][m]
    __shared__ float Bs[32][64];    // [k][n]
    int tid  = threadIdx.x;
    int row0 = blockIdx.x * 64;     // 128 blocks
    int col0 = blockIdx.y * 64;     // 16 blocks
    int tx = tid & 15, ty = tid >> 4;
    float acc[4][4] = {};

    for (int k0 = 0; k0 < EE; k0 += 32) {
#pragma unroll
        for (int i = 0; i < 2; i++) {
            int idx = tid + i * 256;       // float4 slot
            int m   = idx >> 3;
            int k4  = idx & 7;
            float4 av = *(const float4*)(A + (size_t)(row0 + m) * EE + k0 + k4 * 4);
            As[k4 * 4 + 0][m] = av.x; As[k4 * 4 + 1][m] = av.y;
            As[k4 * 4 + 2][m] = av.z; As[k4 * 4 + 3][m] = av.w;
        }
#pragma unroll
        for (int i = 0; i < 2; i++) {
            int idx = tid + i * 256;
            int n   = idx >> 3;
            int k4  = idx & 7;
            int gc  = col0 + n;
            const float* wsrc = (gc < GG) ? (wf + (size_t)gc * EE)
                                          : (wb + (size_t)(gc - GG) * EE);
            float4 bv = *(const float4*)(wsrc + k0 + k4 * 4);
            Bs[k4 * 4 + 0][n] = bv.x; Bs[k4 * 4 + 1][n] = bv.y;
            Bs[k4 * 4 + 2][n] = bv.z; Bs[k4 * 4 + 3][n] = bv.w;
        }
        __syncthreads();
#pragma unroll
        for (int k = 0; k < 32; k++) {
            float a4[4], b4[4];
            *(float4*)a4 = *(const float4*)&As[k][ty * 4];
            *(float4*)b4 = *(const float4*)&Bs[k][tx * 4];
#pragma unroll
            for (int i = 0; i < 4; i++)
#pragma unroll
                for (int j = 0; j < 4; j++)
                    acc[i][j] += a4[i] * b4[j];
        }
        __syncthreads();
    }
#pragma unroll
    for (int i = 0; i < 4; i++) {
        int r = row0 + ty * 4 + i;
#pragma unroll
        for (int j = 0; j < 4; j++) {
            int gc = col0 + tx * 4 + j;
            float bias = (gc < GG) ? (bihf[gc] + bhhf[gc])
                                   : (bihb[gc - GG] + bhhb[gc - GG]);
            C[(size_t)r * 1024 + gc] = acc[i][j] + bias;
        }
    }
}

// ---------------------------------------------------------------------------
// Fast activations
// ---------------------------------------------------------------------------
__device__ __forceinline__ float sigm_f(float x) {
    return 1.f / (1.f + __expf(-x));
}
__device__ __forceinline__ float tanh_f(float x) {
    return 1.f - 2.f / (__expf(2.f * x) + 1.f);
}

// ---------------------------------------------------------------------------
// Kernel 4: LSTM recurrence, v5 = v4 + LDS occupancy pad.
//
// WHY THE PAD (r1-r6 post-mortem): every prior variant plateaued at
// 113-131 us because the allocator pinned VGPRs at 84-88 (high-occupancy
// tier) and SPILLED the 128 weight floats/thread to scratch -> 4.3 GB/step
// L2 reload traffic -> L2-BW wall at ~125 us. Occupancy attributes and asm
// pins do NOT stop spills. Making the block's LDS > 80KB caps achievable
// occupancy at 1 block/CU (8 waves = 2 waves/SIMD), which raises the VGPR
// budget to 256 -> weights become genuinely register-resident. Real
// occupancy is unchanged (128 blocks / 256 CUs was 0.5 blocks/CU anyway).
//
// Structure (verified r4-r6): wave w owns k-slice AND unit-slice
// [16w,16w+16) -> h never crosses waves; partials cross via part[] with ONE
// barrier per step (double-buffered by parity). part[] swizzle keeps all
// LDS access at the free 2-way level.
// ---------------------------------------------------------------------------
__global__ __launch_bounds__(512)
__attribute__((amdgpu_waves_per_eu(2, 2)))
void lstm_rec_k(
    const float* __restrict__ xp,            // [T*B][1024]
    const float* __restrict__ whh_f, const float* __restrict__ whh_b,
    float* __restrict__ hout)                // [2][T][B][H]
{
    int bid = blockIdx.x;
    int dir = bid >> 6;
    int b   = bid & 63;
    int tid = threadIdx.x;
    int wv  = tid >> 6;      // wave id 0..7 -> k-slice and unit-slice
    int l   = tid & 63;
    const float* whh = dir ? whh_b : whh_f;

    // weights: w4[j][k4] = whh[(l+64j)*128 + 16wv + 4k4 .. +3], 128 floats
    float4 w4[8][4];
#pragma unroll
    for (int j = 0; j < 8; j++) {
        const float* src = whh + (size_t)(l + 64 * j) * HH + 16 * wv;
#pragma unroll
        for (int k4 = 0; k4 < 4; k4++)
            w4[j][k4] = *(const float4*)(src + k4 * 4);
    }

    __shared__ __align__(16) float h_lds[HH];      // wave w: [16w,16w+16)
    __shared__ float part[2][8][GG];               // [parity][k-wave][swz gate]
    __shared__ float occ_pad[16000];               // 64 KB: force 1 block/CU

    int t_type = l >> 4;          // 0:i 1:f 2:g 3:o
    int u16    = l & 15;
    int unit   = 16 * wv + u16;
    int g2     = t_type * 128 + unit;              // gate reduced in phase 2
    int phys2  = t_type * 128 + ((unit + 8 * t_type) & 127);

    // phase-1 write indices (swizzled), g = l + 64j
    int physw[8];
#pragma unroll
    for (int j = 0; j < 8; j++) {
        int t = j >> 1;
        physw[j] = t * 128 + ((64 * (j & 1) + l + 8 * t) & 127);
    }

    float c = 0.f;                                 // valid in t_type==0 lanes
    if (l < 16) h_lds[unit] = 0.f;
    // keep occ_pad alive: blockIdx.x < 128 at runtime, unprovable statically
    if (bid == 0x7fffffff) occ_pad[tid] = 1.f;
    __syncthreads();

    int t0   = dir ? (TT - 1) : 0;
    float xg = xp[(size_t)(t0 * BB + b) * 1024 + dir * GG + g2];

    for (int s = 0; s < TT; s++) {
        int p = s & 1;
        // ---- phase 1: partial dots over own k-slice (wave-private h) ----
        float4 h0 = *(const float4*)&h_lds[16 * wv + 0];
        float4 h1 = *(const float4*)&h_lds[16 * wv + 4];
        float4 h2 = *(const float4*)&h_lds[16 * wv + 8];
        float4 h3 = *(const float4*)&h_lds[16 * wv + 12];

#pragma unroll
        for (int j = 0; j < 8; j++) {
            float a0 = w4[j][0].x * h0.x + w4[j][0].y * h0.y
                     + w4[j][0].z * h0.z + w4[j][0].w * h0.w;
            float a1 = w4[j][1].x * h1.x + w4[j][1].y * h1.y
                     + w4[j][1].z * h1.z + w4[j][1].w * h1.w;
            float a2 = w4[j][2].x * h2.x + w4[j][2].y * h2.y
                     + w4[j][2].z * h2.z + w4[j][2].w * h2.w;
            float a3 = w4[j][3].x * h3.x + w4[j][3].y * h3.y
                     + w4[j][3].z * h3.z + w4[j][3].w * h3.w;
            part[p][wv][physw[j]] = (a0 + a1) + (a2 + a3);
        }

        // prefetch next step's xp while FMAs drain
        float xg_next = xg;
        if (s < TT - 1) {
            int tn = dir ? (TT - 2 - s) : (s + 1);
            xg_next = xp[(size_t)(tn * BB + b) * 1024 + dir * GG + g2];
        }
        __syncthreads();

        // ---- phase 2: reduce gate g2, activate, combine, update ----
        float sum = xg;
#pragma unroll
        for (int w2i = 0; w2i < 8; w2i++)
            sum += part[p][w2i][phys2];

        bool is_g = (t_type == 2);
        float e  = __expf(is_g ? (2.f * sum) : (-sum));
        float av = is_g ? (1.f - 2.f / (e + 1.f)) : (1.f / (1.f + e));

        float r1 = __shfl_xor(av, 16);   // t0 lanes: sig(f)
        float r2 = __shfl_xor(av, 32);   // t0 lanes: tanh(g)
        float r3 = __shfl_xor(r1, 32);   // t0 lanes: sig(o)

        if (l < 16) {
            c = r1 * c + av * r2;        // c = sig(f)*c + sig(i)*tanh(g)
            float h = r3 * tanh_f(c);
            h_lds[unit] = h;             // own wave's slice -> no 2nd barrier
            int t = dir ? (TT - 1 - s) : s;
            hout[((size_t)(dir * TT + t) * BB + b) * HH + unit] = h;
        }
        xg = xg_next;
    }
}

// ---------------------------------------------------------------------------
// Kernel 5: head — logits, softmax, argmax, chosen policy. One wave per row.
// ---------------------------------------------------------------------------
__global__ __launch_bounds__(256) void head_k(
    const float* __restrict__ hbuf,           // [2][T][B][H]
    const float* __restrict__ wout, const float* __restrict__ bout,
    float* __restrict__ out)
{
    int wid  = threadIdx.x >> 6;
    int lane = threadIdx.x & 63;
    int row  = blockIdx.x * 4 + wid;          // t*64+b, 0..8191
    int t = row >> 6, b = row & 63;
    const float* hf = hbuf + ((size_t)(t)      * BB + b) * HH;
    const float* hb = hbuf + ((size_t)(TT + t) * BB + b) * HH;

    float l0 = 0.f, l1 = 0.f, v;
    v = hf[lane];      l0 += v * wout[lane];           l1 += v * wout[256 + lane];
    v = hf[lane + 64]; l0 += v * wout[64 + lane];      l1 += v * wout[320 + lane];
    v = hb[lane];      l0 += v * wout[128 + lane];     l1 += v * wout[384 + lane];
    v = hb[lane + 64]; l0 += v * wout[192 + lane];     l1 += v * wout[448 + lane];
#pragma unroll
    for (int off = 32; off > 0; off >>= 1) {
        l0 += __shfl_down(l0, off);
        l1 += __shfl_down(l1, off);
    }
    if (lane == 0) {
        l0 += bout[0]; l1 += bout[1];
        float m  = fmaxf(l0, l1);
        float e0 = __expf(l0 - m), e1 = __expf(l1 - m);
        float inv = 1.f / (e0 + e1);
        float p0 = e0 * inv, p1 = e1 * inv;
        int amax = (l1 > l0) ? 1 : 0;          // tie -> 0, matches jnp.argmax
        out[(size_t)row * 2 + 0] = l0;
        out[(size_t)row * 2 + 1] = l1;
        out[16384 + (size_t)row * 2 + 0] = p0;
        out[16384 + (size_t)row * 2 + 1] = p1;
        out[32768 + row] = amax ? p1 : p0;
        out[40960 + row] = (float)amax;
    }
}

// ---------------------------------------------------------------------------
// Kernel 6: expand utterance mask to tokens, write masked input as float.
// ---------------------------------------------------------------------------
__global__ __launch_bounds__(256) void mask_k(
    const int* __restrict__ x, const int* __restrict__ seg,
    const float* __restrict__ umask, float* __restrict__ out4)
{
    int idx = blockIdx.x * 256 + threadIdx.x;    // < 131072
    int b = idx & 63;
    int s = seg[idx];
    if (s > TT - 1) s = TT - 1;                  // jnp OOB indexing clamps
    if (s < 0) s = 0;
    float keep = umask[s * BB + b];
    out4[idx] = (keep != 0.f) ? (float)x[idx] : 0.f;
}

// ---------------------------------------------------------------------------
extern "C" void kernel_launch(void* const* d_in, const int* in_sizes, int n_in,
                              void* d_out, int out_size, void* d_ws, size_t ws_size,
                              hipStream_t stream)
{
    const int*   x    = (const int*)  d_in[0];
    const float* emb  = (const float*)d_in[1];
    const float* wihf = (const float*)d_in[2];
    const float* whhf = (const float*)d_in[3];
    const float* bihf = (const float*)d_in[4];
    const float* bhhf = (const float*)d_in[5];
    const float* wihb = (const float*)d_in[6];
    const float* whhb = (const float*)d_in[7];
    const float* bihb = (const float*)d_in[8];
    const float* bhhb = (const float*)d_in[9];
    const float* wout = (const float*)d_in[10];
    const float* bout = (const float*)d_in[11];
    float* out = (float*)d_out;
    char*  ws  = (char*)d_ws;

    // workspace layout (bytes)
    int*   seg   = (int*)  (ws + 0);         // 2048*64*4   = 524288
    int*   cnt   = (int*)  (ws + 524288);    // 128*64*4    = 32768
    int*   start = (int*)  (ws + 557056);    // 32768
    float* up    = (float*)(ws + 589824);    // 128*64*256*4  = 8 MB
    float* xp    = (float*)(ws + 8978432);   // 128*64*1024*4 = 32 MB
    float* hbuf  = (float*)(ws + 42532864);  // 2*128*64*128*4 = 8 MB

    segscan_k<<<64, 256, 0, stream>>>(x, seg, cnt, start);
    pool_k<<<2048, 256, 0, stream>>>(x, emb, cnt, start, up);   // 8192 waves
    xp_gemm_k<<<dim3(128, 16), 256, 0, stream>>>(up, wihf, wihb, bihf, bhhf, bihb, bhhb, xp);
    lstm_rec_k<<<128, 512, 0, stream>>>(xp, whhf, whhb, hbuf);
    head_k<<<2048, 256, 0, stream>>>(hbuf, wout, bout, out);
    mask_k<<<512, 256, 0, stream>>>(x, seg, out + 40960, out + 49152);
}

// Round 9
// 324.747 us; speedup vs baseline: 1.0389x; 1.0030x over previous
//
#include <hip/hip_runtime.h>
#include <math.h>

// Problem constants (from reference)
#define LL   2048     // seq len
#define BB   64       // batch
#define EE   256      // embedding
#define HH   128      // lstm hidden per dir
#define GG   512      // 4*H gates
#define TT   128      // utterances (L / SEP_EVERY)
#define SEPT 50256

// ---------------------------------------------------------------------------
// Kernel 1: per-column prefix-scan of SEP flags -> seg[t,b], plus per-(utt,b)
// token counts and start offsets (segments are contiguous per column).
// ---------------------------------------------------------------------------
__global__ __launch_bounds__(256) void segscan_k(
    const int* __restrict__ x, int* __restrict__ seg,
    int* __restrict__ cnt, int* __restrict__ start)
{
    int b   = blockIdx.x;    // 0..63
    int tid = threadIdx.x;   // 0..255, 8 tokens each
    __shared__ int tsum[256];
    __shared__ int ucnt[TT];
    __shared__ int ustart[TT];

    int flags[8];
    int local = 0;
#pragma unroll
    for (int i = 0; i < 8; i++) {
        int t = tid * 8 + i;
        flags[i] = (x[t * BB + b] == SEPT) ? 1 : 0;
        local += flags[i];
    }
    tsum[tid] = local;
    __syncthreads();
    int val = local;
    for (int off = 1; off < 256; off <<= 1) {
        int other = (tid >= off) ? tsum[tid - off] : 0;
        __syncthreads();
        val += other;
        tsum[tid] = val;
        __syncthreads();
    }
    int excl = val - local;   // seps strictly before this thread's chunk

    if (tid < TT) ucnt[tid] = 0;
    __syncthreads();
    int run = excl;
#pragma unroll
    for (int i = 0; i < 8; i++) {
        int t = tid * 8 + i;
        int s = run;                 // seg id = #seps before this token
        seg[t * BB + b] = s;
        run += flags[i];
        if (s < TT) atomicAdd(&ucnt[s], 1);
    }
    __syncthreads();
    if (tid == 0) {
        int acc = 0;
        for (int u = 0; u < TT; u++) { ustart[u] = acc; acc += ucnt[u]; }
    }
    __syncthreads();
    if (tid < TT) {
        cnt[tid * BB + b]   = ucnt[tid];
        start[tid * BB + b] = ustart[tid];
    }
}

// ---------------------------------------------------------------------------
// Kernel 2: embedding gather + mean pool. One WAVE per (utt,b); lane holds a
// float4 column slice -> one coalesced 1KB row read per token. Grid = 2048.
// ---------------------------------------------------------------------------
__global__ __launch_bounds__(256) void pool_k(
    const int* __restrict__ x, const float* __restrict__ emb,
    const int* __restrict__ cnt, const int* __restrict__ start,
    float* __restrict__ up)
{
    int wid  = threadIdx.x >> 6;
    int lane = threadIdx.x & 63;
    int bid  = blockIdx.x * 4 + wid;   // u*64+b, bid in [0,8192)
    int b    = bid & 63;
    int c    = cnt[bid];
    int st   = start[bid];

    float4 acc = {0.f, 0.f, 0.f, 0.f};
    int tok = (c > 0) ? x[st * BB + b] : 0;
    for (int j = 0; j < c; j++) {
        int tok_n = (j + 1 < c) ? x[(st + j + 1) * BB + b] : 0;  // prefetch
        float4 v = ((const float4*)(emb + (size_t)tok * EE))[lane];
        acc.x += v.x; acc.y += v.y; acc.z += v.z; acc.w += v.w;
        tok = tok_n;
    }
    float inv = (c > 0) ? 1.f / (float)c : 0.f;
    float4 r = {acc.x * inv, acc.y * inv, acc.z * inv, acc.w * inv};
    ((float4*)(up + (size_t)bid * EE))[lane] = r;
}

// ---------------------------------------------------------------------------
// Kernel 3: xp = u @ W_cat^T + (b_ih + b_hh).  fp32 register-tiled GEMM.
// ---------------------------------------------------------------------------
__global__ __launch_bounds__(256) void xp_gemm_k(
    const float* __restrict__ A,
    const float* __restrict__ wf, const float* __restrict__ wb,
    const float* __restrict__ bihf, const float* __restrict__ bhhf,
    const float* __restrict__ bihb, const float* __restrict__ bhhb,
    float* __restrict__ C)
{
    __shared__ float As[32][64];    // [k][m]
    __shared__ float Bs[32][64];    // [k][n]
    int tid  = threadIdx.x;
    int row0 = blockIdx.x * 64;     // 128 blocks
    int col0 = blockIdx.y * 64;     // 16 blocks
    int tx = tid & 15, ty = tid >> 4;
    float acc[4][4] = {};

    for (int k0 = 0; k0 < EE; k0 += 32) {
#pragma unroll
        for (int i = 0; i < 2; i++) {
            int idx = tid + i * 256;       // float4 slot
            int m   = idx >> 3;
            int k4  = idx & 7;
            float4 av = *(const float4*)(A + (size_t)(row0 + m) * EE + k0 + k4 * 4);
            As[k4 * 4 + 0][m] = av.x; As[k4 * 4 + 1][m] = av.y;
            As[k4 * 4 + 2][m] = av.z; As[k4 * 4 + 3][m] = av.w;
        }
#pragma unroll
        for (int i = 0; i < 2; i++) {
            int idx = tid + i * 256;
            int n   = idx >> 3;
            int k4  = idx & 7;
            int gc  = col0 + n;
            const float* wsrc = (gc < GG) ? (wf + (size_t)gc * EE)
                                          : (wb + (size_t)(gc - GG) * EE);
            float4 bv = *(const float4*)(wsrc + k0 + k4 * 4);
            Bs[k4 * 4 + 0][n] = bv.x; Bs[k4 * 4 + 1][n] = bv.y;
            Bs[k4 * 4 + 2][n] = bv.z; Bs[k4 * 4 + 3][n] = bv.w;
        }
        __syncthreads();
#pragma unroll
        for (int k = 0; k < 32; k++) {
            float a4[4], b4[4];
            *(float4*)a4 = *(const float4*)&As[k][ty * 4];
            *(float4*)b4 = *(const float4*)&Bs[k][tx * 4];
#pragma unroll
            for (int i = 0; i < 4; i++)
#pragma unroll
                for (int j = 0; j < 4; j++)
                    acc[i][j] += a4[i] * b4[j];
        }
        __syncthreads();
    }
#pragma unroll
    for (int i = 0; i < 4; i++) {
        int r = row0 + ty * 4 + i;
#pragma unroll
        for (int j = 0; j < 4; j++) {
            int gc = col0 + tx * 4 + j;
            float bias = (gc < GG) ? (bihf[gc] + bhhf[gc])
                                   : (bihb[gc - GG] + bhhb[gc - GG]);
            C[(size_t)r * 1024 + gc] = acc[i][j] + bias;
        }
    }
}

// ---------------------------------------------------------------------------
// Fast activations
// ---------------------------------------------------------------------------
__device__ __forceinline__ float sigm_f(float x) {
    return 1.f / (1.f + __expf(-x));
}
__device__ __forceinline__ float tanh_f(float x) {
    return 1.f - 2.f / (__expf(2.f * x) + 1.f);
}

// ---------------------------------------------------------------------------
// Kernel 4: LSTM recurrence, v6 = v4 + REAL LDS occupancy forcing.
//
// r1-r7 saga: every variant plateaued at 113-131 us = L2-BW wall (4.3 GB
// of per-step weight reloads / 34.5 TB/s). Root cause: with 33 KB static
// LDS the RA sees 4 blocks/CU achievable, targets the high-occupancy tier
// (88 VGPRs), and SINKS the rematerializable weight loads into the K-loop.
// r6's guarded occ_pad store was dead-store-eliminated (LDS stores are not
// observable -> DSE -> array dropped; LDS_Block_Size stayed 33280).
//
// Fix: fold the pad into the genuinely-used, dynamically-indexed part[]
// array: [2][8][1280] = 80 KB (+h = 82.4 KB static). DCE cannot shrink a
// live dynamically-indexed array. 160/82.4 -> 1 block/CU achievable -> RA
// target = 2 waves/SIMD -> 256-VGPR budget -> weights stay resident.
// Real occupancy unchanged (128 blocks / 256 CUs = 0.5 blocks/CU).
// Row stride 1280 === 0 mod 32: bank behavior identical to verified r6.
// ---------------------------------------------------------------------------
#define PSTR 1280
__global__ __launch_bounds__(512)
__attribute__((amdgpu_waves_per_eu(2, 2)))
void lstm_rec_k(
    const float* __restrict__ xp,            // [T*B][1024]
    const float* __restrict__ whh_f, const float* __restrict__ whh_b,
    float* __restrict__ hout)                // [2][T][B][H]
{
    int bid = blockIdx.x;
    int dir = bid >> 6;
    int b   = bid & 63;
    int tid = threadIdx.x;
    int wv  = tid >> 6;      // wave id 0..7 -> k-slice and unit-slice
    int l   = tid & 63;
    const float* whh = dir ? whh_b : whh_f;

    // weights: w4[j][k4] = whh[(l+64j)*128 + 16wv + 4k4 .. +3], 128 floats
    float4 w4[8][4];
#pragma unroll
    for (int j = 0; j < 8; j++) {
        const float* src = whh + (size_t)(l + 64 * j) * HH + 16 * wv;
#pragma unroll
        for (int k4 = 0; k4 < 4; k4++)
            w4[j][k4] = *(const float4*)(src + k4 * 4);
    }

    __shared__ __align__(16) float h_lds[HH];      // wave w: [16w,16w+16)
    __shared__ float part[2][8][PSTR];             // 80 KB: pad forces 1 blk/CU

    int t_type = l >> 4;          // 0:i 1:f 2:g 3:o
    int u16    = l & 15;
    int unit   = 16 * wv + u16;
    int g2     = t_type * 128 + unit;              // gate reduced in phase 2
    int phys2  = t_type * 128 + ((unit + 8 * t_type) & 127);

    // phase-1 write indices (swizzled), g = l + 64j
    int physw[8];
#pragma unroll
    for (int j = 0; j < 8; j++) {
        int t = j >> 1;
        physw[j] = t * 128 + ((64 * (j & 1) + l + 8 * t) & 127);
    }

    float c = 0.f;                                 // valid in t_type==0 lanes
    if (l < 16) h_lds[unit] = 0.f;
    __syncthreads();

    int t0   = dir ? (TT - 1) : 0;
    float xg = xp[(size_t)(t0 * BB + b) * 1024 + dir * GG + g2];

    for (int s = 0; s < TT; s++) {
        int p = s & 1;
        // ---- phase 1: partial dots over own k-slice (wave-private h) ----
        float4 h0 = *(const float4*)&h_lds[16 * wv + 0];
        float4 h1 = *(const float4*)&h_lds[16 * wv + 4];
        float4 h2 = *(const float4*)&h_lds[16 * wv + 8];
        float4 h3 = *(const float4*)&h_lds[16 * wv + 12];

#pragma unroll
        for (int j = 0; j < 8; j++) {
            float a0 = w4[j][0].x * h0.x + w4[j][0].y * h0.y
                     + w4[j][0].z * h0.z + w4[j][0].w * h0.w;
            float a1 = w4[j][1].x * h1.x + w4[j][1].y * h1.y
                     + w4[j][1].z * h1.z + w4[j][1].w * h1.w;
            float a2 = w4[j][2].x * h2.x + w4[j][2].y * h2.y
                     + w4[j][2].z * h2.z + w4[j][2].w * h2.w;
            float a3 = w4[j][3].x * h3.x + w4[j][3].y * h3.y
                     + w4[j][3].z * h3.z + w4[j][3].w * h3.w;
            part[p][wv][physw[j]] = (a0 + a1) + (a2 + a3);
        }

        // prefetch next step's xp while FMAs drain
        float xg_next = xg;
        if (s < TT - 1) {
            int tn = dir ? (TT - 2 - s) : (s + 1);
            xg_next = xp[(size_t)(tn * BB + b) * 1024 + dir * GG + g2];
        }
        __syncthreads();

        // ---- phase 2: reduce gate g2, activate, combine, update ----
        float sum = xg;
#pragma unroll
        for (int w2i = 0; w2i < 8; w2i++)
            sum += part[p][w2i][phys2];

        bool is_g = (t_type == 2);
        float e  = __expf(is_g ? (2.f * sum) : (-sum));
        float av = is_g ? (1.f - 2.f / (e + 1.f)) : (1.f / (1.f + e));

        float r1 = __shfl_xor(av, 16);   // t0 lanes: sig(f)
        float r2 = __shfl_xor(av, 32);   // t0 lanes: tanh(g)
        float r3 = __shfl_xor(r1, 32);   // t0 lanes: sig(o)

        if (l < 16) {
            c = r1 * c + av * r2;        // c = sig(f)*c + sig(i)*tanh(g)
            float h = r3 * tanh_f(c);
            h_lds[unit] = h;             // own wave's slice -> no 2nd barrier
            int t = dir ? (TT - 1 - s) : s;
            hout[((size_t)(dir * TT + t) * BB + b) * HH + unit] = h;
        }
        xg = xg_next;
    }
}

// ---------------------------------------------------------------------------
// Kernel 5: head — logits, softmax, argmax, chosen policy. One wave per row.
// ---------------------------------------------------------------------------
__global__ __launch_bounds__(256) void head_k(
    const float* __restrict__ hbuf,           // [2][T][B][H]
    const float* __restrict__ wout, const float* __restrict__ bout,
    float* __restrict__ out)
{
    int wid  = threadIdx.x >> 6;
    int lane = threadIdx.x & 63;
    int row  = blockIdx.x * 4 + wid;          // t*64+b, 0..8191
    int t = row >> 6, b = row & 63;
    const float* hf = hbuf + ((size_t)(t)      * BB + b) * HH;
    const float* hb = hbuf + ((size_t)(TT + t) * BB + b) * HH;

    float l0 = 0.f, l1 = 0.f, v;
    v = hf[lane];      l0 += v * wout[lane];           l1 += v * wout[256 + lane];
    v = hf[lane + 64]; l0 += v * wout[64 + lane];      l1 += v * wout[320 + lane];
    v = hb[lane];      l0 += v * wout[128 + lane];     l1 += v * wout[384 + lane];
    v = hb[lane + 64]; l0 += v * wout[192 + lane];     l1 += v * wout[448 + lane];
#pragma unroll
    for (int off = 32; off > 0; off >>= 1) {
        l0 += __shfl_down(l0, off);
        l1 += __shfl_down(l1, off);
    }
    if (lane == 0) {
        l0 += bout[0]; l1 += bout[1];
        float m  = fmaxf(l0, l1);
        float e0 = __expf(l0 - m), e1 = __expf(l1 - m);
        float inv = 1.f / (e0 + e1);
        float p0 = e0 * inv, p1 = e1 * inv;
        int amax = (l1 > l0) ? 1 : 0;          // tie -> 0, matches jnp.argmax
        out[(size_t)row * 2 + 0] = l0;
        out[(size_t)row * 2 + 1] = l1;
        out[16384 + (size_t)row * 2 + 0] = p0;
        out[16384 + (size_t)row * 2 + 1] = p1;
        out[32768 + row] = amax ? p1 : p0;
        out[40960 + row] = (float)amax;
    }
}

// ---------------------------------------------------------------------------
// Kernel 6: expand utterance mask to tokens, write masked input as float.
// ---------------------------------------------------------------------------
__global__ __launch_bounds__(256) void mask_k(
    const int* __restrict__ x, const int* __restrict__ seg,
    const float* __restrict__ umask, float* __restrict__ out4)
{
    int idx = blockIdx.x * 256 + threadIdx.x;    // < 131072
    int b = idx & 63;
    int s = seg[idx];
    if (s > TT - 1) s = TT - 1;                  // jnp OOB indexing clamps
    if (s < 0) s = 0;
    float keep = umask[s * BB + b];
    out4[idx] = (keep != 0.f) ? (float)x[idx] : 0.f;
}

// ---------------------------------------------------------------------------
extern "C" void kernel_launch(void* const* d_in, const int* in_sizes, int n_in,
                              void* d_out, int out_size, void* d_ws, size_t ws_size,
                              hipStream_t stream)
{
    const int*   x    = (const int*)  d_in[0];
    const float* emb  = (const float*)d_in[1];
    const float* wihf = (const float*)d_in[2];
    const float* whhf = (const float*)d_in[3];
    const float* bihf = (const float*)d_in[4];
    const float* bhhf = (const float*)d_in[5];
    const float* wihb = (const float*)d_in[6];
    const float* whhb = (const float*)d_in[7];
    const float* bihb = (const float*)d_in[8];
    const float* bhhb = (const float*)d_in[9];
    const float* wout = (const float*)d_in[10];
    const float* bout = (const float*)d_in[11];
    float* out = (float*)d_out;
    char*  ws  = (char*)d_ws;

    // workspace layout (bytes)
    int*   seg   = (int*)  (ws + 0);         // 2048*64*4   = 524288
    int*   cnt   = (int*)  (ws + 524288);    // 128*64*4    = 32768
    int*   start = (int*)  (ws + 557056);    // 32768
    float* up    = (float*)(ws + 589824);    // 128*64*256*4  = 8 MB
    float* xp    = (float*)(ws + 8978432);   // 128*64*1024*4 = 32 MB
    float* hbuf  = (float*)(ws + 42532864);  // 2*128*64*128*4 = 8 MB

    segscan_k<<<64, 256, 0, stream>>>(x, seg, cnt, start);
    pool_k<<<2048, 256, 0, stream>>>(x, emb, cnt, start, up);   // 8192 waves
    xp_gemm_k<<<dim3(128, 16), 256, 0, stream>>>(up, wihf, wihb, bihf, bhhf, bihb, bhhb, xp);
    lstm_rec_k<<<128, 512, 0, stream>>>(xp, whhf, whhb, hbuf);
    head_k<<<2048, 256, 0, stream>>>(hbuf, wout, bout, out);
    mask_k<<<512, 256, 0, stream>>>(x, seg, out + 40960, out + 49152);
}